// Round 1
// 398.375 us; speedup vs baseline: 1.0749x; 1.0749x over previous
//
#include <hip/hip_runtime.h>
#include <math.h>

#define N_NODES 50000
#define N_PAD   50016                 // padded to 32-row gemm tiles
#define N_EDGES 800000
#define E_TOT   (N_EDGES + N_NODES)   // edges + self-loops = 850000
#define F_IN    256
#define NHEAD   8
#define CH      32
#define HC      256                   // NHEAD*CH
#define OUT_C   40
#define NEG_SLOPE 0.2f
#define SCAN_BLOCKS ((N_NODES + 255) / 256)   // 196
#define G_XCVT  ((N_NODES * F_IN / 8 + 255) / 256)   // 6250
#define G_WCVT  ((HC * F_IN + 255) / 256)            // 256
#define G_WCVT2 ((HC * CH + 255) / 256)              // 32

typedef unsigned short u16;
typedef unsigned int   u32;
typedef unsigned char  u8;
typedef __attribute__((ext_vector_type(8))) short bf16x8;   // 4 VGPRs
typedef __attribute__((ext_vector_type(4))) float f32x4;
typedef __attribute__((ext_vector_type(2))) float f32x2;

__device__ __forceinline__ u16 f2bf(float f) {
    union { u32 u; float f; } x; x.f = f;
    u32 u = x.u;
    return (u16)((u + 0x7fffu + ((u >> 16) & 1u)) >> 16);   // round-nearest-even
}
__device__ __forceinline__ float bflo(u32 v) {
    union { u32 u; float f; } x; x.u = v << 16; return x.f;
}
// fp8 e4m3 encode (1 byte) / packed decode (2 floats per op) — gfx950 native
__device__ __forceinline__ u8 f2fp8(float f) {
    return (u8)(__builtin_amdgcn_cvt_pk_fp8_f32(f, f, 0, false) & 0xff);
}

// ht8 is fp8 e4m3 in NATURAL (head-major) layout: ht8[node*256 + h*32 + c].
// This is the raw gemm output column order (col = h*32+c), so gemm stores are
// identity and each attn lane owns ONE head -> no per-edge cross-lane ops.

// ================= fused prep: x->bf16, W1->bf16^T, W2->bf16^T (one launch)
__global__ __launch_bounds__(256) void cvt_kernel(const float* __restrict__ x,
        u16* __restrict__ xb, const float* __restrict__ W1, u16* __restrict__ Wt,
        const float* __restrict__ W2, u16* __restrict__ W2t) {
    int b = blockIdx.x;
    if (b < G_XCVT) {
        int t = b * 256 + threadIdx.x;               // one per 8 elements
        if (t >= N_NODES * F_IN / 8) return;
        const float4* xp = (const float4*)x + (size_t)t * 2;
        float4 v0 = xp[0], v1 = xp[1];
        uint4 o;
        o.x = (u32)f2bf(v0.x) | ((u32)f2bf(v0.y) << 16);
        o.y = (u32)f2bf(v0.z) | ((u32)f2bf(v0.w) << 16);
        o.z = (u32)f2bf(v1.x) | ((u32)f2bf(v1.y) << 16);
        o.w = (u32)f2bf(v1.z) | ((u32)f2bf(v1.w) << 16);
        ((uint4*)xb)[t] = o;
    } else if (b < G_XCVT + G_WCVT) {
        int t = (b - G_XCVT) * 256 + threadIdx.x;    // 65536 total
        int n = t & 255, k = t >> 8;                 // coalesced reads
        Wt[(size_t)n * F_IN + k] = f2bf(W1[(size_t)k * HC + n]);
    } else {
        int t = (b - G_XCVT - G_WCVT) * 256 + threadIdx.x;  // 8192 total
        if (t >= HC * CH) return;
        int n = t & 255, k = t >> 8;
        W2t[(size_t)n * CH + k] = f2bf(W2[(size_t)k * HC + n]);
    }
}

// ================= GEMM1 via MFMA bf16: ht8 = fp8(x @ W1), natural store
__global__ __launch_bounds__(256) void gemm1_mfma(const u16* __restrict__ xb,
        const u16* __restrict__ Wt, u8* __restrict__ ht8) {
    const int row0 = blockIdx.x * 32;
    const int t    = threadIdx.x;
    const int wave = t >> 6;
    const int lane = t & 63;
    const int l16  = lane & 15;
    const int quad = lane >> 4;
    const int nb   = wave * 64;

    f32x4 acc[2][4];
    #pragma unroll
    for (int m = 0; m < 2; ++m)
        #pragma unroll
        for (int n = 0; n < 4; ++n) acc[m][n] = (f32x4){0.f, 0.f, 0.f, 0.f};

    const u16* a0p = xb + (size_t)(row0 + l16) * F_IN;        // M-tile 0
    const u16* a1p = a0p + 16 * F_IN;                         // M-tile 1
    const u16* bp  = Wt + (size_t)(nb + l16) * F_IN;          // N-tile stride 16*F_IN

    #pragma unroll 1
    for (int k0 = 0; k0 < F_IN; k0 += 32) {
        const int ko = k0 + quad * 8;
        bf16x8 a0 = *(const bf16x8*)(a0p + ko);
        bf16x8 a1 = *(const bf16x8*)(a1p + ko);
        bf16x8 b0 = *(const bf16x8*)(bp + 0 * 16 * F_IN + ko);
        bf16x8 b1 = *(const bf16x8*)(bp + 1 * 16 * F_IN + ko);
        bf16x8 b2 = *(const bf16x8*)(bp + 2 * 16 * F_IN + ko);
        bf16x8 b3 = *(const bf16x8*)(bp + 3 * 16 * F_IN + ko);
        acc[0][0] = __builtin_amdgcn_mfma_f32_16x16x32_bf16(a0, b0, acc[0][0], 0, 0, 0);
        acc[0][1] = __builtin_amdgcn_mfma_f32_16x16x32_bf16(a0, b1, acc[0][1], 0, 0, 0);
        acc[0][2] = __builtin_amdgcn_mfma_f32_16x16x32_bf16(a0, b2, acc[0][2], 0, 0, 0);
        acc[0][3] = __builtin_amdgcn_mfma_f32_16x16x32_bf16(a0, b3, acc[0][3], 0, 0, 0);
        acc[1][0] = __builtin_amdgcn_mfma_f32_16x16x32_bf16(a1, b0, acc[1][0], 0, 0, 0);
        acc[1][1] = __builtin_amdgcn_mfma_f32_16x16x32_bf16(a1, b1, acc[1][1], 0, 0, 0);
        acc[1][2] = __builtin_amdgcn_mfma_f32_16x16x32_bf16(a1, b2, acc[1][2], 0, 0, 0);
        acc[1][3] = __builtin_amdgcn_mfma_f32_16x16x32_bf16(a1, b3, acc[1][3], 0, 0, 0);
    }

    #pragma unroll
    for (int m = 0; m < 2; ++m) {
        #pragma unroll
        for (int r = 0; r < 4; ++r) {
            int row = row0 + m * 16 + quad * 4 + r;
            if (row < N_NODES) {
                u8* hr = ht8 + (size_t)row * HC;
                #pragma unroll
                for (int n = 0; n < 4; ++n) {
                    int col = nb + n * 16 + l16;
                    hr[col] = f2fp8(acc[m][n][r]);   // natural layout
                }
            }
        }
    }
}

// ================= GEMM2 via MFMA bf16: ht8 = fp8(hmb @ W2), K=32 single step
__global__ __launch_bounds__(256) void gemm2_mfma(const u16* __restrict__ hmb,
        const u16* __restrict__ W2t, u8* __restrict__ ht8) {
    const int row0 = blockIdx.x * 32;
    const int t    = threadIdx.x;
    const int wave = t >> 6;
    const int lane = t & 63;
    const int l16  = lane & 15;
    const int quad = lane >> 4;
    const int nb   = wave * 64;
    const int ko   = quad * 8;

    const u16* a0p = hmb + (size_t)(row0 + l16) * CH;
    const u16* a1p = a0p + 16 * CH;
    const u16* bp  = W2t + (size_t)(nb + l16) * CH;

    bf16x8 a0 = *(const bf16x8*)(a0p + ko);
    bf16x8 a1 = *(const bf16x8*)(a1p + ko);
    bf16x8 b0 = *(const bf16x8*)(bp + 0 * 16 * CH + ko);
    bf16x8 b1 = *(const bf16x8*)(bp + 1 * 16 * CH + ko);
    bf16x8 b2 = *(const bf16x8*)(bp + 2 * 16 * CH + ko);
    bf16x8 b3 = *(const bf16x8*)(bp + 3 * 16 * CH + ko);

    f32x4 z = (f32x4){0.f, 0.f, 0.f, 0.f};
    f32x4 acc[2][4];
    acc[0][0] = __builtin_amdgcn_mfma_f32_16x16x32_bf16(a0, b0, z, 0, 0, 0);
    acc[0][1] = __builtin_amdgcn_mfma_f32_16x16x32_bf16(a0, b1, z, 0, 0, 0);
    acc[0][2] = __builtin_amdgcn_mfma_f32_16x16x32_bf16(a0, b2, z, 0, 0, 0);
    acc[0][3] = __builtin_amdgcn_mfma_f32_16x16x32_bf16(a0, b3, z, 0, 0, 0);
    acc[1][0] = __builtin_amdgcn_mfma_f32_16x16x32_bf16(a1, b0, z, 0, 0, 0);
    acc[1][1] = __builtin_amdgcn_mfma_f32_16x16x32_bf16(a1, b1, z, 0, 0, 0);
    acc[1][2] = __builtin_amdgcn_mfma_f32_16x16x32_bf16(a1, b2, z, 0, 0, 0);
    acc[1][3] = __builtin_amdgcn_mfma_f32_16x16x32_bf16(a1, b3, z, 0, 0, 0);

    #pragma unroll
    for (int m = 0; m < 2; ++m) {
        #pragma unroll
        for (int r = 0; r < 4; ++r) {
            int row = row0 + m * 16 + quad * 4 + r;
            if (row < N_NODES) {
                u8* hr = ht8 + (size_t)row * HC;
                #pragma unroll
                for (int n = 0; n < 4; ++n) {
                    int col = nb + n * 16 + l16;
                    hr[col] = f2fp8(acc[m][n][r]);   // natural layout
                }
            }
        }
    }
}

// ================= alpha from fp8 ht (head-major): thread = node
__global__ __launch_bounds__(256) void alpha_t_kernel(const u8* __restrict__ ht8,
        const float* __restrict__ a_src, const float* __restrict__ a_dst,
        float* __restrict__ asrc, float* __restrict__ adst) {
    __shared__ float sas[HC], sad[HC];
    for (int i = threadIdx.x; i < HC; i += 256) {
        sas[i] = a_src[i];
        sad[i] = a_dst[i];
    }
    __syncthreads();
    int node = blockIdx.x * 256 + threadIdx.x;
    if (node >= N_NODES) return;
    const uint2* hp = (const uint2*)(ht8 + (size_t)node * HC);   // 32 uint2
    float s1[NHEAD], s2[NHEAD];
    #pragma unroll
    for (int h = 0; h < NHEAD; ++h) {
        float t1 = 0.f, t2 = 0.f;
        #pragma unroll
        for (int i = 0; i < 4; ++i) {
            uint2 v = hp[h * 4 + i];                  // channels i*8 .. i*8+7
            f32x2 p01 = __builtin_amdgcn_cvt_pk_f32_fp8(v.x, false);
            f32x2 p23 = __builtin_amdgcn_cvt_pk_f32_fp8(v.x, true);
            f32x2 p45 = __builtin_amdgcn_cvt_pk_f32_fp8(v.y, false);
            f32x2 p67 = __builtin_amdgcn_cvt_pk_f32_fp8(v.y, true);
            const float* s1p = &sas[h * CH + i * 8];  // broadcast (same addr)
            const float* s2p = &sad[h * CH + i * 8];
            t1 += p01.x * s1p[0] + p01.y * s1p[1] + p23.x * s1p[2] + p23.y * s1p[3]
                + p45.x * s1p[4] + p45.y * s1p[5] + p67.x * s1p[6] + p67.y * s1p[7];
            t2 += p01.x * s2p[0] + p01.y * s2p[1] + p23.x * s2p[2] + p23.y * s2p[3]
                + p45.x * s2p[4] + p45.y * s2p[5] + p67.x * s2p[6] + p67.y * s2p[7];
        }
        s1[h] = t1; s2[h] = t2;
    }
    float4* o1 = (float4*)(asrc + (size_t)node * NHEAD);
    float4* o2 = (float4*)(adst + (size_t)node * NHEAD);
    o1[0] = make_float4(s1[0], s1[1], s1[2], s1[3]);
    o1[1] = make_float4(s1[4], s1[5], s1[6], s1[7]);
    o2[0] = make_float4(s2[0], s2[1], s2[2], s2[3]);
    o2[1] = make_float4(s2[4], s2[5], s2[6], s2[7]);
}

// ================= CSR build =================
__global__ __launch_bounds__(256) void deg_kernel(const int* __restrict__ ei,
        int* __restrict__ deg) {
    int j = blockIdx.x * 256 + threadIdx.x;
    if (j >= E_TOT) return;
    int dst = (j < N_EDGES) ? ei[N_EDGES + j] : (j - N_EDGES);
    atomicAdd(&deg[dst], 1);
}

__device__ __forceinline__ int wave_incl_scan(int v, int lane) {
    #pragma unroll
    for (int d = 1; d < 64; d <<= 1) {
        int u = __shfl_up(v, d, 64);
        if (lane >= d) v += u;
    }
    return v;
}

__global__ __launch_bounds__(256) void scan1_kernel(const int* __restrict__ deg,
        int* __restrict__ rowptr, int* __restrict__ partials) {
    const int t    = blockIdx.x * 256 + threadIdx.x;
    const int lane = threadIdx.x & 63;
    const int wid  = threadIdx.x >> 6;
    int v = (t < N_NODES) ? deg[t] : 0;
    int inc = wave_incl_scan(v, lane);
    __shared__ int wtot[4];
    if (lane == 63) wtot[wid] = inc;
    __syncthreads();
    int woff = 0;
    #pragma unroll
    for (int i = 0; i < 4; ++i) woff += (i < wid) ? wtot[i] : 0;
    if (t < N_NODES) rowptr[t] = inc - v + woff;      // block-local exclusive
    if (threadIdx.x == 255) partials[blockIdx.x] = woff + inc;  // block total
}

__global__ __launch_bounds__(256) void scan2_kernel(int* __restrict__ partials) {
    const int t    = threadIdx.x;
    const int lane = t & 63;
    const int wid  = t >> 6;
    int v = (t < SCAN_BLOCKS) ? partials[t] : 0;
    int inc = wave_incl_scan(v, lane);
    __shared__ int wtot[4];
    if (lane == 63) wtot[wid] = inc;
    __syncthreads();
    int woff = 0;
    #pragma unroll
    for (int i = 0; i < 4; ++i) woff += (i < wid) ? wtot[i] : 0;
    __syncthreads();
    if (t < SCAN_BLOCKS) partials[t] = inc - v + woff;
}

__global__ __launch_bounds__(256) void scan3_kernel(int* __restrict__ rowptr,
        int* __restrict__ cursor, const int* __restrict__ partials) {
    const int t = blockIdx.x * 256 + threadIdx.x;
    if (t < N_NODES) {
        int v = rowptr[t] + partials[blockIdx.x];
        rowptr[t] = v;
        cursor[t] = v;
    } else if (t == N_NODES) {
        rowptr[N_NODES] = E_TOT;
    }
}

__global__ __launch_bounds__(256) void scatter_kernel(const int* __restrict__ ei,
        int* __restrict__ cursor, int* __restrict__ csr_src) {
    int j = blockIdx.x * 256 + threadIdx.x;
    if (j >= E_TOT) return;
    int src, dst;
    if (j < N_EDGES) { src = ei[j]; dst = ei[N_EDGES + j]; }
    else             { src = j - N_EDGES; dst = src; }
    int pos = atomicAdd(&cursor[dst], 1);
    csr_src[pos] = src;
}

// ================= fused attention: one WAVE per dst node.
// r16: latency-bound at depth-1 prefetch (VALUBusy 40%, 20% HBM). Now:
//  - halves of the wave process even/odd edges (2x MLP, no degree divergence)
//  - depth-2 rotating prefetch per half (~4 gathers in flight per wave)
//  - head-major fp8 layout: lane = head*4 + chblk, owns 8 channels of ONE
//    head -> per-edge weight is lane-local, zero per-edge cross-lane ops.
// Epilogue: xor-32 half fold, per-head 1/wsum, xor-4/8/16 head-mean butterfly.
__global__ __launch_bounds__(256) void attn_kernel(const int* __restrict__ rowptr,
        const int* __restrict__ csr_src, const float* __restrict__ asrc,
        const float* __restrict__ adst, const u8* __restrict__ ht8,
        const float* __restrict__ b, u16* __restrict__ out) {
    const int wid = (blockIdx.x * 256 + threadIdx.x) >> 6;   // dst node
    if (wid >= N_NODES) return;
    const int dst  = wid;
    const int lane = threadIdx.x & 63;
    const int half = lane >> 5;          // edge parity this half handles
    const int l32  = lane & 31;
    const int h    = l32 >> 2;           // owned head
    const int c0   = (l32 & 3) * 8;      // owned channel block
    const float ad_own = adst[dst * NHEAD + h];
    const uint2* H8 = (const uint2*)ht8; // node row = 32 uint2; lane reads #l32

    float acc0 = 0.f, acc1 = 0.f, acc2 = 0.f, acc3 = 0.f;
    float acc4 = 0.f, acc5 = 0.f, acc6 = 0.f, acc7 = 0.f;
    float wsum = 0.f;

    const int p0 = rowptr[dst], p1 = rowptr[dst + 1];

    // rotating depth-2 pipeline (named buffers: no runtime-indexed arrays)
    float asA = 0.f, asB = 0.f;
    uint2 hvA = make_uint2(0u, 0u), hvB = make_uint2(0u, 0u);
    int e = p0 + half;
    if (e < p1) {
        int s = csr_src[e];
        asA = asrc[s * NHEAD + h];
        hvA = H8[(size_t)s * 32 + l32];
    }
    if (e + 2 < p1) {
        int s = csr_src[e + 2];
        asB = asrc[s * NHEAD + h];
        hvB = H8[(size_t)s * 32 + l32];
    }

    while (e < p1) {
        // ---- consume A (edge e) ----
        {
            float x = asA + ad_own;
            x = x > 0.f ? x : NEG_SLOPE * x;
            float w = __expf(x);
            wsum += w;
            f32x2 p01 = __builtin_amdgcn_cvt_pk_f32_fp8(hvA.x, false);
            f32x2 p23 = __builtin_amdgcn_cvt_pk_f32_fp8(hvA.x, true);
            f32x2 p45 = __builtin_amdgcn_cvt_pk_f32_fp8(hvA.y, false);
            f32x2 p67 = __builtin_amdgcn_cvt_pk_f32_fp8(hvA.y, true);
            acc0 += w * p01.x;  acc1 += w * p01.y;
            acc2 += w * p23.x;  acc3 += w * p23.y;
            acc4 += w * p45.x;  acc5 += w * p45.y;
            acc6 += w * p67.x;  acc7 += w * p67.y;
        }
        // refill A (edge e+4) — in flight across B-consume + next A-consume
        if (e + 4 < p1) {
            int s = csr_src[e + 4];
            asA = asrc[s * NHEAD + h];
            hvA = H8[(size_t)s * 32 + l32];
        }
        // ---- consume B (edge e+2) ----
        if (e + 2 < p1) {
            float x = asB + ad_own;
            x = x > 0.f ? x : NEG_SLOPE * x;
            float w = __expf(x);
            wsum += w;
            f32x2 p01 = __builtin_amdgcn_cvt_pk_f32_fp8(hvB.x, false);
            f32x2 p23 = __builtin_amdgcn_cvt_pk_f32_fp8(hvB.x, true);
            f32x2 p45 = __builtin_amdgcn_cvt_pk_f32_fp8(hvB.y, false);
            f32x2 p67 = __builtin_amdgcn_cvt_pk_f32_fp8(hvB.y, true);
            acc0 += w * p01.x;  acc1 += w * p01.y;
            acc2 += w * p23.x;  acc3 += w * p23.y;
            acc4 += w * p45.x;  acc5 += w * p45.y;
            acc6 += w * p67.x;  acc7 += w * p67.y;
        }
        // refill B (edge e+6)
        if (e + 6 < p1) {
            int s = csr_src[e + 6];
            asB = asrc[s * NHEAD + h];
            hvB = H8[(size_t)s * 32 + l32];
        }
        e += 4;
    }

    // ---- fold the two halves (same head/channels, disjoint edges) ----
    acc0 += __shfl_xor(acc0, 32, 64);  acc1 += __shfl_xor(acc1, 32, 64);
    acc2 += __shfl_xor(acc2, 32, 64);  acc3 += __shfl_xor(acc3, 32, 64);
    acc4 += __shfl_xor(acc4, 32, 64);  acc5 += __shfl_xor(acc5, 32, 64);
    acc6 += __shfl_xor(acc6, 32, 64);  acc7 += __shfl_xor(acc7, 32, 64);
    wsum += __shfl_xor(wsum, 32, 64);

    // ---- per-head softmax normalize ----
    float winv = 1.0f / wsum;
    acc0 *= winv; acc1 *= winv; acc2 *= winv; acc3 *= winv;
    acc4 *= winv; acc5 *= winv; acc6 *= winv; acc7 *= winv;

    // ---- sum over heads: butterfly xor 4, 8, 16 (within 32-lane groups) ----
    acc0 += __shfl_xor(acc0,  4, 64);  acc1 += __shfl_xor(acc1,  4, 64);
    acc2 += __shfl_xor(acc2,  4, 64);  acc3 += __shfl_xor(acc3,  4, 64);
    acc4 += __shfl_xor(acc4,  4, 64);  acc5 += __shfl_xor(acc5,  4, 64);
    acc6 += __shfl_xor(acc6,  4, 64);  acc7 += __shfl_xor(acc7,  4, 64);
    acc0 += __shfl_xor(acc0,  8, 64);  acc1 += __shfl_xor(acc1,  8, 64);
    acc2 += __shfl_xor(acc2,  8, 64);  acc3 += __shfl_xor(acc3,  8, 64);
    acc4 += __shfl_xor(acc4,  8, 64);  acc5 += __shfl_xor(acc5,  8, 64);
    acc6 += __shfl_xor(acc6,  8, 64);  acc7 += __shfl_xor(acc7,  8, 64);
    acc0 += __shfl_xor(acc0, 16, 64);  acc1 += __shfl_xor(acc1, 16, 64);
    acc2 += __shfl_xor(acc2, 16, 64);  acc3 += __shfl_xor(acc3, 16, 64);
    acc4 += __shfl_xor(acc4, 16, 64);  acc5 += __shfl_xor(acc5, 16, 64);
    acc6 += __shfl_xor(acc6, 16, 64);  acc7 += __shfl_xor(acc7, 16, 64);

    // ---- lanes 0..3 hold the head-mean for channel blocks 0,8,16,24 ----
    if (lane < 4) {
        const float4* bp4 = (const float4*)b;
        float4 blo = bp4[c0 / 4], bhi = bp4[c0 / 4 + 1];
        float v0 = acc0 * 0.125f + blo.x;
        float v1 = acc1 * 0.125f + blo.y;
        float v2 = acc2 * 0.125f + blo.z;
        float v3 = acc3 * 0.125f + blo.w;
        float v4 = acc4 * 0.125f + bhi.x;
        float v5 = acc5 * 0.125f + bhi.y;
        float v6 = acc6 * 0.125f + bhi.z;
        float v7 = acc7 * 0.125f + bhi.w;
        v0 = v0 > 0.f ? v0 : (__expf(v0) - 1.f);
        v1 = v1 > 0.f ? v1 : (__expf(v1) - 1.f);
        v2 = v2 > 0.f ? v2 : (__expf(v2) - 1.f);
        v3 = v3 > 0.f ? v3 : (__expf(v3) - 1.f);
        v4 = v4 > 0.f ? v4 : (__expf(v4) - 1.f);
        v5 = v5 > 0.f ? v5 : (__expf(v5) - 1.f);
        v6 = v6 > 0.f ? v6 : (__expf(v6) - 1.f);
        v7 = v7 > 0.f ? v7 : (__expf(v7) - 1.f);
        uint4 o;
        o.x = (u32)f2bf(v0) | ((u32)f2bf(v1) << 16);
        o.y = (u32)f2bf(v2) | ((u32)f2bf(v3) << 16);
        o.z = (u32)f2bf(v4) | ((u32)f2bf(v5) << 16);
        o.w = (u32)f2bf(v6) | ((u32)f2bf(v7) << 16);
        *(uint4*)(out + (size_t)dst * CH + c0) = o;
    }
}

// ================= output head: 4 nodes/block (1 wave each), log_softmax
__global__ __launch_bounds__(256) void out_kernel(const u16* __restrict__ hf,
        const float* __restrict__ Wo, const float* __restrict__ bo,
        float* __restrict__ out) {
    const int wave = threadIdx.x >> 6;
    const int lane = threadIdx.x & 63;
    const int n    = blockIdx.x * 4 + wave;
    __shared__ float hs[4][CH];
    if (n < N_NODES && lane < CH) hs[wave][lane] = bflo((u32)hf[n * CH + lane]);
    __syncthreads();
    if (n >= N_NODES) return;
    float logit = -INFINITY;
    if (lane < OUT_C) {
        float a = bo[lane];
        #pragma unroll
        for (int k = 0; k < CH; ++k) a += hs[wave][k] * Wo[k * OUT_C + lane];
        logit = a;
    }
    float m = logit;
    #pragma unroll
    for (int off = 32; off; off >>= 1) m = fmaxf(m, __shfl_xor(m, off, 64));
    float ex = (lane < OUT_C) ? __expf(logit - m) : 0.f;
    float ssum = ex;
    #pragma unroll
    for (int off = 32; off; off >>= 1) ssum += __shfl_xor(ssum, off, 64);
    if (lane < OUT_C) out[(size_t)n * OUT_C + lane] = logit - m - __logf(ssum);
}

extern "C" void kernel_launch(void* const* d_in, const int* in_sizes, int n_in,
                              void* d_out, int out_size, void* d_ws, size_t ws_size,
                              hipStream_t stream) {
    const float* x      = (const float*)d_in[0];
    const int*   ei     = (const int*)  d_in[1];
    const float* W1     = (const float*)d_in[2];
    const float* a_src1 = (const float*)d_in[3];
    const float* a_dst1 = (const float*)d_in[4];
    const float* b1     = (const float*)d_in[5];
    const float* W2     = (const float*)d_in[6];
    const float* a_src2 = (const float*)d_in[7];
    const float* a_dst2 = (const float*)d_in[8];
    const float* b2     = (const float*)d_in[9];
    const float* Wo     = (const float*)d_in[10];
    const float* bo     = (const float*)d_in[11];
    float* out = (float*)d_out;

    // workspace carve-up (256B-aligned)
    char* ws = (char*)d_ws;
    size_t off = 0;
    auto carve = [&](size_t bytes) { char* p = ws + off; off += (bytes + 255) & ~(size_t)255; return p; };
    u8*    ht8     = (u8*)   carve((size_t)N_NODES * HC);          // 12.8 MB (fp8, head-major)
    u16*   xb      = (u16*)  carve((size_t)N_PAD * F_IN * 2);      // 25.6 MB (bf16 x, padded)
    u16*   Wt      = (u16*)  carve((size_t)HC * F_IN * 2);         // 128 KB (bf16 W1^T)
    u16*   W2t     = (u16*)  carve((size_t)HC * CH * 2);           // 16 KB (bf16 W2^T)
    float* asrc    = (float*)carve((size_t)N_NODES * NHEAD * 4);   // 1.6 MB
    float* adst    = (float*)carve((size_t)N_NODES * NHEAD * 4);
    u16*   hmid    = (u16*)  carve((size_t)N_PAD * CH * 2);        // 3.2 MB (bf16)
    u16*   hout    = (u16*)  carve((size_t)N_NODES * CH * 2);      // 3.2 MB (bf16)
    int*   deg     = (int*)  carve((size_t)N_NODES * 4);
    int*   rowptr  = (int*)  carve((size_t)(N_NODES + 1) * 4);
    int*   cursor  = (int*)  carve((size_t)N_NODES * 4);
    int*   csr_src = (int*)  carve((size_t)E_TOT * 4);             // 3.4 MB
    int*   partials= (int*)  carve((size_t)SCAN_BLOCKS * 4);

    const int g_cvt   = G_XCVT + G_WCVT + G_WCVT2;           // 6538
    const int g_gemm  = (N_NODES + 31) / 32;                 // 1563
    const int g_node  = (N_NODES + 255) / 256;               // 196
    const int g_edge  = (E_TOT + 255) / 256;                 // 3321
    const int g_attn  = (N_NODES * 64 + 255) / 256;          // 12500 (wave/dst)
    const int g_out   = (N_NODES + 3) / 4;                   // 12500

    // ---------- prep + CSR build ----------
    cvt_kernel<<<g_cvt, 256, 0, stream>>>(x, xb, W1, Wt, W2, W2t);
    (void)hipMemsetAsync(deg, 0, (size_t)N_NODES * 4, stream);
    deg_kernel<<<g_edge, 256, 0, stream>>>(ei, deg);
    scan1_kernel<<<SCAN_BLOCKS, 256, 0, stream>>>(deg, rowptr, partials);
    scan2_kernel<<<1, 256, 0, stream>>>(partials);
    scan3_kernel<<<SCAN_BLOCKS, 256, 0, stream>>>(rowptr, cursor, partials);
    scatter_kernel<<<g_edge, 256, 0, stream>>>(ei, cursor, csr_src);

    // ---------- layer 1 ----------
    gemm1_mfma<<<g_gemm, 256, 0, stream>>>(xb, Wt, ht8);
    alpha_t_kernel<<<g_node, 256, 0, stream>>>(ht8, a_src1, a_dst1, asrc, adst);
    attn_kernel<<<g_attn, 256, 0, stream>>>(rowptr, csr_src, asrc, adst, ht8, b1, hmid);

    // ---------- layer 2 ----------
    gemm2_mfma<<<g_gemm, 256, 0, stream>>>(hmid, W2t, ht8);
    alpha_t_kernel<<<g_node, 256, 0, stream>>>(ht8, a_src2, a_dst2, asrc, adst);
    attn_kernel<<<g_attn, 256, 0, stream>>>(rowptr, csr_src, asrc, adst, ht8, b2, hout);

    // ---------- output head ----------
    out_kernel<<<g_out, 256, 0, stream>>>(hout, Wo, bo, out);
}

// Round 2
// 394.427 us; speedup vs baseline: 1.0856x; 1.0100x over previous
//
#include <hip/hip_runtime.h>
#include <math.h>

#define N_NODES 50000
#define N_PAD   50016                 // padded to 32-row gemm tiles
#define N_EDGES 800000
#define E_TOT   (N_EDGES + N_NODES)   // edges + self-loops = 850000
#define F_IN    256
#define NHEAD   8
#define CH      32
#define HC      256                   // NHEAD*CH
#define OUT_C   40
#define NEG_SLOPE 0.2f
#define SCAN_BLOCKS ((N_NODES + 255) / 256)   // 196
#define G_XCVT  ((N_NODES * F_IN / 8 + 255) / 256)   // 6250
#define G_WCVT  ((HC * F_IN + 255) / 256)            // 256
#define G_WCVT2 ((HC * CH + 255) / 256)              // 32

typedef unsigned short u16;
typedef unsigned int   u32;
typedef unsigned char  u8;
typedef __attribute__((ext_vector_type(8))) short bf16x8;   // 4 VGPRs
typedef __attribute__((ext_vector_type(4))) float f32x4;
typedef __attribute__((ext_vector_type(2))) float f32x2;

__device__ __forceinline__ u16 f2bf(float f) {
    union { u32 u; float f; } x; x.f = f;
    u32 u = x.u;
    return (u16)((u + 0x7fffu + ((u >> 16) & 1u)) >> 16);   // round-nearest-even
}
__device__ __forceinline__ float bflo(u32 v) {
    union { u32 u; float f; } x; x.u = v << 16; return x.f;
}
// fp8 e4m3 encode (1 byte) / packed decode (2 floats per op) — gfx950 native
__device__ __forceinline__ u8 f2fp8(float f) {
    return (u8)(__builtin_amdgcn_cvt_pk_fp8_f32(f, f, 0, false) & 0xff);
}

// ht8 is fp8 e4m3 in NATURAL (head-major) layout: ht8[node*256 + h*32 + c].
// gemm stores are identity; in attn a 16-lane quarter reads one row as uint4.

// ================= fused prep: x->bf16, W1->bf16^T, W2->bf16^T (one launch)
__global__ __launch_bounds__(256) void cvt_kernel(const float* __restrict__ x,
        u16* __restrict__ xb, const float* __restrict__ W1, u16* __restrict__ Wt,
        const float* __restrict__ W2, u16* __restrict__ W2t) {
    int b = blockIdx.x;
    if (b < G_XCVT) {
        int t = b * 256 + threadIdx.x;               // one per 8 elements
        if (t >= N_NODES * F_IN / 8) return;
        const float4* xp = (const float4*)x + (size_t)t * 2;
        float4 v0 = xp[0], v1 = xp[1];
        uint4 o;
        o.x = (u32)f2bf(v0.x) | ((u32)f2bf(v0.y) << 16);
        o.y = (u32)f2bf(v0.z) | ((u32)f2bf(v0.w) << 16);
        o.z = (u32)f2bf(v1.x) | ((u32)f2bf(v1.y) << 16);
        o.w = (u32)f2bf(v1.z) | ((u32)f2bf(v1.w) << 16);
        ((uint4*)xb)[t] = o;
    } else if (b < G_XCVT + G_WCVT) {
        int t = (b - G_XCVT) * 256 + threadIdx.x;    // 65536 total
        int n = t & 255, k = t >> 8;                 // coalesced reads
        Wt[(size_t)n * F_IN + k] = f2bf(W1[(size_t)k * HC + n]);
    } else {
        int t = (b - G_XCVT - G_WCVT) * 256 + threadIdx.x;  // 8192 total
        if (t >= HC * CH) return;
        int n = t & 255, k = t >> 8;
        W2t[(size_t)n * CH + k] = f2bf(W2[(size_t)k * HC + n]);
    }
}

// ================= GEMM1 via MFMA bf16: ht8 = fp8(x @ W1), natural store
__global__ __launch_bounds__(256) void gemm1_mfma(const u16* __restrict__ xb,
        const u16* __restrict__ Wt, u8* __restrict__ ht8) {
    const int row0 = blockIdx.x * 32;
    const int t    = threadIdx.x;
    const int wave = t >> 6;
    const int lane = t & 63;
    const int l16  = lane & 15;
    const int quad = lane >> 4;
    const int nb   = wave * 64;

    f32x4 acc[2][4];
    #pragma unroll
    for (int m = 0; m < 2; ++m)
        #pragma unroll
        for (int n = 0; n < 4; ++n) acc[m][n] = (f32x4){0.f, 0.f, 0.f, 0.f};

    const u16* a0p = xb + (size_t)(row0 + l16) * F_IN;        // M-tile 0
    const u16* a1p = a0p + 16 * F_IN;                         // M-tile 1
    const u16* bp  = Wt + (size_t)(nb + l16) * F_IN;          // N-tile stride 16*F_IN

    #pragma unroll 1
    for (int k0 = 0; k0 < F_IN; k0 += 32) {
        const int ko = k0 + quad * 8;
        bf16x8 a0 = *(const bf16x8*)(a0p + ko);
        bf16x8 a1 = *(const bf16x8*)(a1p + ko);
        bf16x8 b0 = *(const bf16x8*)(bp + 0 * 16 * F_IN + ko);
        bf16x8 b1 = *(const bf16x8*)(bp + 1 * 16 * F_IN + ko);
        bf16x8 b2 = *(const bf16x8*)(bp + 2 * 16 * F_IN + ko);
        bf16x8 b3 = *(const bf16x8*)(bp + 3 * 16 * F_IN + ko);
        acc[0][0] = __builtin_amdgcn_mfma_f32_16x16x32_bf16(a0, b0, acc[0][0], 0, 0, 0);
        acc[0][1] = __builtin_amdgcn_mfma_f32_16x16x32_bf16(a0, b1, acc[0][1], 0, 0, 0);
        acc[0][2] = __builtin_amdgcn_mfma_f32_16x16x32_bf16(a0, b2, acc[0][2], 0, 0, 0);
        acc[0][3] = __builtin_amdgcn_mfma_f32_16x16x32_bf16(a0, b3, acc[0][3], 0, 0, 0);
        acc[1][0] = __builtin_amdgcn_mfma_f32_16x16x32_bf16(a1, b0, acc[1][0], 0, 0, 0);
        acc[1][1] = __builtin_amdgcn_mfma_f32_16x16x32_bf16(a1, b1, acc[1][1], 0, 0, 0);
        acc[1][2] = __builtin_amdgcn_mfma_f32_16x16x32_bf16(a1, b2, acc[1][2], 0, 0, 0);
        acc[1][3] = __builtin_amdgcn_mfma_f32_16x16x32_bf16(a1, b3, acc[1][3], 0, 0, 0);
    }

    #pragma unroll
    for (int m = 0; m < 2; ++m) {
        #pragma unroll
        for (int r = 0; r < 4; ++r) {
            int row = row0 + m * 16 + quad * 4 + r;
            if (row < N_NODES) {
                u8* hr = ht8 + (size_t)row * HC;
                #pragma unroll
                for (int n = 0; n < 4; ++n) {
                    int col = nb + n * 16 + l16;
                    hr[col] = f2fp8(acc[m][n][r]);   // natural layout
                }
            }
        }
    }
}

// ================= GEMM2 via MFMA bf16: ht8 = fp8(hmb @ W2), K=32 single step
__global__ __launch_bounds__(256) void gemm2_mfma(const u16* __restrict__ hmb,
        const u16* __restrict__ W2t, u8* __restrict__ ht8) {
    const int row0 = blockIdx.x * 32;
    const int t    = threadIdx.x;
    const int wave = t >> 6;
    const int lane = t & 63;
    const int l16  = lane & 15;
    const int quad = lane >> 4;
    const int nb   = wave * 64;
    const int ko   = quad * 8;

    const u16* a0p = hmb + (size_t)(row0 + l16) * CH;
    const u16* a1p = a0p + 16 * CH;
    const u16* bp  = W2t + (size_t)(nb + l16) * CH;

    bf16x8 a0 = *(const bf16x8*)(a0p + ko);
    bf16x8 a1 = *(const bf16x8*)(a1p + ko);
    bf16x8 b0 = *(const bf16x8*)(bp + 0 * 16 * CH + ko);
    bf16x8 b1 = *(const bf16x8*)(bp + 1 * 16 * CH + ko);
    bf16x8 b2 = *(const bf16x8*)(bp + 2 * 16 * CH + ko);
    bf16x8 b3 = *(const bf16x8*)(bp + 3 * 16 * CH + ko);

    f32x4 z = (f32x4){0.f, 0.f, 0.f, 0.f};
    f32x4 acc[2][4];
    acc[0][0] = __builtin_amdgcn_mfma_f32_16x16x32_bf16(a0, b0, z, 0, 0, 0);
    acc[0][1] = __builtin_amdgcn_mfma_f32_16x16x32_bf16(a0, b1, z, 0, 0, 0);
    acc[0][2] = __builtin_amdgcn_mfma_f32_16x16x32_bf16(a0, b2, z, 0, 0, 0);
    acc[0][3] = __builtin_amdgcn_mfma_f32_16x16x32_bf16(a0, b3, z, 0, 0, 0);
    acc[1][0] = __builtin_amdgcn_mfma_f32_16x16x32_bf16(a1, b0, z, 0, 0, 0);
    acc[1][1] = __builtin_amdgcn_mfma_f32_16x16x32_bf16(a1, b1, z, 0, 0, 0);
    acc[1][2] = __builtin_amdgcn_mfma_f32_16x16x32_bf16(a1, b2, z, 0, 0, 0);
    acc[1][3] = __builtin_amdgcn_mfma_f32_16x16x32_bf16(a1, b3, z, 0, 0, 0);

    #pragma unroll
    for (int m = 0; m < 2; ++m) {
        #pragma unroll
        for (int r = 0; r < 4; ++r) {
            int row = row0 + m * 16 + quad * 4 + r;
            if (row < N_NODES) {
                u8* hr = ht8 + (size_t)row * HC;
                #pragma unroll
                for (int n = 0; n < 4; ++n) {
                    int col = nb + n * 16 + l16;
                    hr[col] = f2fp8(acc[m][n][r]);   // natural layout
                }
            }
        }
    }
}

// ================= alpha from fp8 ht (head-major): thread = node
__global__ __launch_bounds__(256) void alpha_t_kernel(const u8* __restrict__ ht8,
        const float* __restrict__ a_src, const float* __restrict__ a_dst,
        float* __restrict__ asrc, float* __restrict__ adst) {
    __shared__ float sas[HC], sad[HC];
    for (int i = threadIdx.x; i < HC; i += 256) {
        sas[i] = a_src[i];
        sad[i] = a_dst[i];
    }
    __syncthreads();
    int node = blockIdx.x * 256 + threadIdx.x;
    if (node >= N_NODES) return;
    const uint2* hp = (const uint2*)(ht8 + (size_t)node * HC);   // 32 uint2
    float s1[NHEAD], s2[NHEAD];
    #pragma unroll
    for (int h = 0; h < NHEAD; ++h) {
        float t1 = 0.f, t2 = 0.f;
        #pragma unroll
        for (int i = 0; i < 4; ++i) {
            uint2 v = hp[h * 4 + i];                  // channels i*8 .. i*8+7
            f32x2 p01 = __builtin_amdgcn_cvt_pk_f32_fp8(v.x, false);
            f32x2 p23 = __builtin_amdgcn_cvt_pk_f32_fp8(v.x, true);
            f32x2 p45 = __builtin_amdgcn_cvt_pk_f32_fp8(v.y, false);
            f32x2 p67 = __builtin_amdgcn_cvt_pk_f32_fp8(v.y, true);
            const float* s1p = &sas[h * CH + i * 8];  // broadcast (same addr)
            const float* s2p = &sad[h * CH + i * 8];
            t1 += p01.x * s1p[0] + p01.y * s1p[1] + p23.x * s1p[2] + p23.y * s1p[3]
                + p45.x * s1p[4] + p45.y * s1p[5] + p67.x * s1p[6] + p67.y * s1p[7];
            t2 += p01.x * s2p[0] + p01.y * s2p[1] + p23.x * s2p[2] + p23.y * s2p[3]
                + p45.x * s2p[4] + p45.y * s2p[5] + p67.x * s2p[6] + p67.y * s2p[7];
        }
        s1[h] = t1; s2[h] = t2;
    }
    float4* o1 = (float4*)(asrc + (size_t)node * NHEAD);
    float4* o2 = (float4*)(adst + (size_t)node * NHEAD);
    o1[0] = make_float4(s1[0], s1[1], s1[2], s1[3]);
    o1[1] = make_float4(s1[4], s1[5], s1[6], s1[7]);
    o2[0] = make_float4(s2[0], s2[1], s2[2], s2[3]);
    o2[1] = make_float4(s2[4], s2[5], s2[6], s2[7]);
}

// ================= CSR build =================
__global__ __launch_bounds__(256) void deg_kernel(const int* __restrict__ ei,
        int* __restrict__ deg) {
    int j = blockIdx.x * 256 + threadIdx.x;
    if (j >= E_TOT) return;
    int dst = (j < N_EDGES) ? ei[N_EDGES + j] : (j - N_EDGES);
    atomicAdd(&deg[dst], 1);
}

__device__ __forceinline__ int wave_incl_scan(int v, int lane) {
    #pragma unroll
    for (int d = 1; d < 64; d <<= 1) {
        int u = __shfl_up(v, d, 64);
        if (lane >= d) v += u;
    }
    return v;
}

__global__ __launch_bounds__(256) void scan1_kernel(const int* __restrict__ deg,
        int* __restrict__ rowptr, int* __restrict__ partials) {
    const int t    = blockIdx.x * 256 + threadIdx.x;
    const int lane = threadIdx.x & 63;
    const int wid  = threadIdx.x >> 6;
    int v = (t < N_NODES) ? deg[t] : 0;
    int inc = wave_incl_scan(v, lane);
    __shared__ int wtot[4];
    if (lane == 63) wtot[wid] = inc;
    __syncthreads();
    int woff = 0;
    #pragma unroll
    for (int i = 0; i < 4; ++i) woff += (i < wid) ? wtot[i] : 0;
    if (t < N_NODES) rowptr[t] = inc - v + woff;      // block-local exclusive
    if (threadIdx.x == 255) partials[blockIdx.x] = woff + inc;  // block total
}

__global__ __launch_bounds__(256) void scan2_kernel(int* __restrict__ partials) {
    const int t    = threadIdx.x;
    const int lane = t & 63;
    const int wid  = t >> 6;
    int v = (t < SCAN_BLOCKS) ? partials[t] : 0;
    int inc = wave_incl_scan(v, lane);
    __shared__ int wtot[4];
    if (lane == 63) wtot[wid] = inc;
    __syncthreads();
    int woff = 0;
    #pragma unroll
    for (int i = 0; i < 4; ++i) woff += (i < wid) ? wtot[i] : 0;
    __syncthreads();
    if (t < SCAN_BLOCKS) partials[t] = inc - v + woff;
}

__global__ __launch_bounds__(256) void scan3_kernel(int* __restrict__ rowptr,
        int* __restrict__ cursor, const int* __restrict__ partials) {
    const int t = blockIdx.x * 256 + threadIdx.x;
    if (t < N_NODES) {
        int v = rowptr[t] + partials[blockIdx.x];
        rowptr[t] = v;
        cursor[t] = v;
    } else if (t == N_NODES) {
        rowptr[N_NODES] = E_TOT;
    }
}

__global__ __launch_bounds__(256) void scatter_kernel(const int* __restrict__ ei,
        int* __restrict__ cursor, int* __restrict__ csr_src) {
    int j = blockIdx.x * 256 + threadIdx.x;
    if (j >= E_TOT) return;
    int src, dst;
    if (j < N_EDGES) { src = ei[j]; dst = ei[N_EDGES + j]; }
    else             { src = j - N_EDGES; dst = src; }
    int pos = atomicAdd(&cursor[dst], 1);
    csr_src[pos] = src;
}

// ================= fused attention: one WAVE per dst node, QUARTER per edge.
// r17: r16 (half per edge) was still latency-bound (VALUBusy 59%, HBM 24%) —
// with 2 edges/phase the degree-17 loop was ~8 serial trips. Now 16 lanes own
// one edge (uint4 = 16B of the 256B row each), so a wave runs 4 edges/phase
// and depth-2 prefetch keeps 8 edges (2KB) in flight; mean trips/quarter ~2.
// Lane l16 owns head h=l16>>1, channel block (l16&1)*16. Per-edge weight is
// lane-local (exp redundancy 2 lanes/head). Epilogue: xor16/32 quarter-fold,
// per-head 1/wsum, xor2/4/8 head-mean fold; lanes 0-1 store 16 bf16 each.
__global__ __launch_bounds__(256) void attn_kernel(const int* __restrict__ rowptr,
        const int* __restrict__ csr_src, const float* __restrict__ asrc,
        const float* __restrict__ adst, const u8* __restrict__ ht8,
        const float* __restrict__ b, u16* __restrict__ out) {
    const int wid = (blockIdx.x * 256 + threadIdx.x) >> 6;   // dst node
    if (wid >= N_NODES) return;
    const int dst  = wid;
    const int lane = threadIdx.x & 63;
    const int q    = lane >> 4;          // quarter -> edge offset
    const int l16  = lane & 15;
    const int h    = l16 >> 1;           // owned head
    const float ad_own = adst[dst * NHEAD + h];

    float acc[16];
    #pragma unroll
    for (int i = 0; i < 16; ++i) acc[i] = 0.f;
    float wsum = 0.f;

    auto consume = [&](float as_, const uint4& hv) {
        float x = as_ + ad_own;
        x = x > 0.f ? x : NEG_SLOPE * x;
        float w = __expf(x);
        wsum += w;
        f32x2 d;
        d = __builtin_amdgcn_cvt_pk_f32_fp8(hv.x, false); acc[ 0] += w * d.x; acc[ 1] += w * d.y;
        d = __builtin_amdgcn_cvt_pk_f32_fp8(hv.x, true ); acc[ 2] += w * d.x; acc[ 3] += w * d.y;
        d = __builtin_amdgcn_cvt_pk_f32_fp8(hv.y, false); acc[ 4] += w * d.x; acc[ 5] += w * d.y;
        d = __builtin_amdgcn_cvt_pk_f32_fp8(hv.y, true ); acc[ 6] += w * d.x; acc[ 7] += w * d.y;
        d = __builtin_amdgcn_cvt_pk_f32_fp8(hv.z, false); acc[ 8] += w * d.x; acc[ 9] += w * d.y;
        d = __builtin_amdgcn_cvt_pk_f32_fp8(hv.z, true ); acc[10] += w * d.x; acc[11] += w * d.y;
        d = __builtin_amdgcn_cvt_pk_f32_fp8(hv.w, false); acc[12] += w * d.x; acc[13] += w * d.y;
        d = __builtin_amdgcn_cvt_pk_f32_fp8(hv.w, true ); acc[14] += w * d.x; acc[15] += w * d.y;
    };

    const int p0 = rowptr[dst], p1 = rowptr[dst + 1];
    const int boff = l16 * 16;           // byte offset of this lane's uint4

    // rotating depth-2 pipeline (named buffers: no runtime-indexed arrays)
    float asA = 0.f, asB = 0.f;
    uint4 hvA = make_uint4(0u, 0u, 0u, 0u), hvB = make_uint4(0u, 0u, 0u, 0u);
    int eA = p0 + q;                      // this quarter's edges: stride 4
    int eB = eA + 4;
    if (eA < p1) {
        int s = csr_src[eA];
        asA = asrc[s * NHEAD + h];
        hvA = *(const uint4*)(ht8 + (size_t)s * HC + boff);
    }
    if (eB < p1) {
        int s = csr_src[eB];
        asB = asrc[s * NHEAD + h];
        hvB = *(const uint4*)(ht8 + (size_t)s * HC + boff);
    }

    while (eA < p1) {
        consume(asA, hvA);                // edge eA (valid: loop predicate)
        if (eA + 8 < p1) {                // refill A (edge eA+8)
            int s = csr_src[eA + 8];
            asA = asrc[s * NHEAD + h];
            hvA = *(const uint4*)(ht8 + (size_t)s * HC + boff);
        }
        if (eB < p1) consume(asB, hvB);   // edge eB
        if (eB + 8 < p1) {                // refill B (edge eB+8)
            int s = csr_src[eB + 8];
            asB = asrc[s * NHEAD + h];
            hvB = *(const uint4*)(ht8 + (size_t)s * HC + boff);
        }
        eA += 8; eB += 8;
    }

    // ---- fold the four quarters (same (h,chblk), disjoint edges) ----
    #pragma unroll
    for (int i = 0; i < 16; ++i) {
        acc[i] += __shfl_xor(acc[i], 16, 64);
        acc[i] += __shfl_xor(acc[i], 32, 64);
    }
    wsum += __shfl_xor(wsum, 16, 64);
    wsum += __shfl_xor(wsum, 32, 64);

    // ---- per-head softmax normalize ----
    float winv = 1.0f / wsum;
    #pragma unroll
    for (int i = 0; i < 16; ++i) acc[i] *= winv;

    // ---- sum over heads: lane = 2h + blk, fold bits 1..3 ----
    #pragma unroll
    for (int i = 0; i < 16; ++i) {
        acc[i] += __shfl_xor(acc[i], 2, 64);
        acc[i] += __shfl_xor(acc[i], 4, 64);
        acc[i] += __shfl_xor(acc[i], 8, 64);
    }

    // ---- lane 0: channels 0..15, lane 1: channels 16..31 ----
    if (lane < 2) {
        const int c0 = lane * 16;
        const float4* bp4 = (const float4*)(b + c0);
        float4 b0 = bp4[0], b1 = bp4[1], b2 = bp4[2], b3 = bp4[3];
        float bb[16] = {b0.x, b0.y, b0.z, b0.w, b1.x, b1.y, b1.z, b1.w,
                        b2.x, b2.y, b2.z, b2.w, b3.x, b3.y, b3.z, b3.w};
        u32 d[8];
        #pragma unroll
        for (int i = 0; i < 8; ++i) {
            float v0 = acc[2 * i]     * 0.125f + bb[2 * i];
            float v1 = acc[2 * i + 1] * 0.125f + bb[2 * i + 1];
            v0 = v0 > 0.f ? v0 : (__expf(v0) - 1.f);
            v1 = v1 > 0.f ? v1 : (__expf(v1) - 1.f);
            d[i] = (u32)f2bf(v0) | ((u32)f2bf(v1) << 16);
        }
        uint4* op = (uint4*)(out + (size_t)dst * CH + c0);
        op[0] = make_uint4(d[0], d[1], d[2], d[3]);
        op[1] = make_uint4(d[4], d[5], d[6], d[7]);
    }
}

// ================= output head: 4 nodes/block (1 wave each), log_softmax
__global__ __launch_bounds__(256) void out_kernel(const u16* __restrict__ hf,
        const float* __restrict__ Wo, const float* __restrict__ bo,
        float* __restrict__ out) {
    const int wave = threadIdx.x >> 6;
    const int lane = threadIdx.x & 63;
    const int n    = blockIdx.x * 4 + wave;
    __shared__ float hs[4][CH];
    if (n < N_NODES && lane < CH) hs[wave][lane] = bflo((u32)hf[n * CH + lane]);
    __syncthreads();
    if (n >= N_NODES) return;
    float logit = -INFINITY;
    if (lane < OUT_C) {
        float a = bo[lane];
        #pragma unroll
        for (int k = 0; k < CH; ++k) a += hs[wave][k] * Wo[k * OUT_C + lane];
        logit = a;
    }
    float m = logit;
    #pragma unroll
    for (int off = 32; off; off >>= 1) m = fmaxf(m, __shfl_xor(m, off, 64));
    float ex = (lane < OUT_C) ? __expf(logit - m) : 0.f;
    float ssum = ex;
    #pragma unroll
    for (int off = 32; off; off >>= 1) ssum += __shfl_xor(ssum, off, 64);
    if (lane < OUT_C) out[(size_t)n * OUT_C + lane] = logit - m - __logf(ssum);
}

extern "C" void kernel_launch(void* const* d_in, const int* in_sizes, int n_in,
                              void* d_out, int out_size, void* d_ws, size_t ws_size,
                              hipStream_t stream) {
    const float* x      = (const float*)d_in[0];
    const int*   ei     = (const int*)  d_in[1];
    const float* W1     = (const float*)d_in[2];
    const float* a_src1 = (const float*)d_in[3];
    const float* a_dst1 = (const float*)d_in[4];
    const float* b1     = (const float*)d_in[5];
    const float* W2     = (const float*)d_in[6];
    const float* a_src2 = (const float*)d_in[7];
    const float* a_dst2 = (const float*)d_in[8];
    const float* b2     = (const float*)d_in[9];
    const float* Wo     = (const float*)d_in[10];
    const float* bo     = (const float*)d_in[11];
    float* out = (float*)d_out;

    // workspace carve-up (256B-aligned)
    char* ws = (char*)d_ws;
    size_t off = 0;
    auto carve = [&](size_t bytes) { char* p = ws + off; off += (bytes + 255) & ~(size_t)255; return p; };
    u8*    ht8     = (u8*)   carve((size_t)N_NODES * HC);          // 12.8 MB (fp8, head-major)
    u16*   xb      = (u16*)  carve((size_t)N_PAD * F_IN * 2);      // 25.6 MB (bf16 x, padded)
    u16*   Wt      = (u16*)  carve((size_t)HC * F_IN * 2);         // 128 KB (bf16 W1^T)
    u16*   W2t     = (u16*)  carve((size_t)HC * CH * 2);           // 16 KB (bf16 W2^T)
    float* asrc    = (float*)carve((size_t)N_NODES * NHEAD * 4);   // 1.6 MB
    float* adst    = (float*)carve((size_t)N_NODES * NHEAD * 4);
    u16*   hmid    = (u16*)  carve((size_t)N_PAD * CH * 2);        // 3.2 MB (bf16)
    u16*   hout    = (u16*)  carve((size_t)N_NODES * CH * 2);      // 3.2 MB (bf16)
    int*   deg     = (int*)  carve((size_t)N_NODES * 4);
    int*   rowptr  = (int*)  carve((size_t)(N_NODES + 1) * 4);
    int*   cursor  = (int*)  carve((size_t)N_NODES * 4);
    int*   csr_src = (int*)  carve((size_t)E_TOT * 4);             // 3.4 MB
    int*   partials= (int*)  carve((size_t)SCAN_BLOCKS * 4);

    const int g_cvt   = G_XCVT + G_WCVT + G_WCVT2;           // 6538
    const int g_gemm  = (N_NODES + 31) / 32;                 // 1563
    const int g_node  = (N_NODES + 255) / 256;               // 196
    const int g_edge  = (E_TOT + 255) / 256;                 // 3321
    const int g_attn  = (N_NODES * 64 + 255) / 256;          // 12500 (wave/dst)
    const int g_out   = (N_NODES + 3) / 4;                   // 12500

    // ---------- prep + CSR build ----------
    cvt_kernel<<<g_cvt, 256, 0, stream>>>(x, xb, W1, Wt, W2, W2t);
    (void)hipMemsetAsync(deg, 0, (size_t)N_NODES * 4, stream);
    deg_kernel<<<g_edge, 256, 0, stream>>>(ei, deg);
    scan1_kernel<<<SCAN_BLOCKS, 256, 0, stream>>>(deg, rowptr, partials);
    scan2_kernel<<<1, 256, 0, stream>>>(partials);
    scan3_kernel<<<SCAN_BLOCKS, 256, 0, stream>>>(rowptr, cursor, partials);
    scatter_kernel<<<g_edge, 256, 0, stream>>>(ei, cursor, csr_src);

    // ---------- layer 1 ----------
    gemm1_mfma<<<g_gemm, 256, 0, stream>>>(xb, Wt, ht8);
    alpha_t_kernel<<<g_node, 256, 0, stream>>>(ht8, a_src1, a_dst1, asrc, adst);
    attn_kernel<<<g_attn, 256, 0, stream>>>(rowptr, csr_src, asrc, adst, ht8, b1, hmid);

    // ---------- layer 2 ----------
    gemm2_mfma<<<g_gemm, 256, 0, stream>>>(hmid, W2t, ht8);
    alpha_t_kernel<<<g_node, 256, 0, stream>>>(ht8, a_src2, a_dst2, asrc, adst);
    attn_kernel<<<g_attn, 256, 0, stream>>>(rowptr, csr_src, asrc, adst, ht8, b2, hout);

    // ---------- output head ----------
    out_kernel<<<g_out, 256, 0, stream>>>(hout, Wo, bo, out);
}

// Round 3
// 382.998 us; speedup vs baseline: 1.1180x; 1.0298x over previous
//
#include <hip/hip_runtime.h>
#include <math.h>

#define N_NODES 50000
#define N_PAD   50016                 // padded to 32-row gemm tiles
#define N_EDGES 800000
#define E_TOT   (N_EDGES + N_NODES)   // edges + self-loops = 850000
#define F_IN    256
#define NHEAD   8
#define CH      32
#define HC      256                   // NHEAD*CH
#define OUT_C   40
#define NEG_SLOPE 0.2f
#define SCAN_BLOCKS ((N_NODES + 255) / 256)   // 196
#define G_DEG   ((E_TOT + 255) / 256)                // 3321
#define G_XCVT  ((N_NODES * F_IN / 8 + 255) / 256)   // 6250
#define G_WCVT  ((HC * F_IN + 255) / 256)            // 256
#define G_WCVT2 ((HC * CH + 255) / 256)              // 32

typedef unsigned short u16;
typedef unsigned int   u32;
typedef unsigned char  u8;
typedef __attribute__((ext_vector_type(8))) short bf16x8;   // 4 VGPRs
typedef __attribute__((ext_vector_type(4))) float f32x4;
typedef __attribute__((ext_vector_type(2))) float f32x2;

__device__ __forceinline__ u16 f2bf(float f) {
    union { u32 u; float f; } x; x.f = f;
    u32 u = x.u;
    return (u16)((u + 0x7fffu + ((u >> 16) & 1u)) >> 16);   // round-nearest-even
}
__device__ __forceinline__ float bflo(u32 v) {
    union { u32 u; float f; } x; x.u = v << 16; return x.f;
}
// fp8 e4m3 encode (1 byte) / packed decode (2 floats per op) — gfx950 native
__device__ __forceinline__ u8 f2fp8(float f) {
    return (u8)(__builtin_amdgcn_cvt_pk_fp8_f32(f, f, 0, false) & 0xff);
}

// ht8 is fp8 e4m3 in NATURAL (head-major) layout: ht8[node*256 + h*32 + c].
// gemm stores are identity; in attn a 16-lane quarter reads one row as uint4.
// NOTE: f2fp8 of finite inputs saturates (never emits NaN bytes) — attn's
// stale-prefetch-register trick relies on decoded fp8 always being finite.

// ===== fused prep: deg atomics + x->bf16 + W1->bf16^T + W2->bf16^T (one launch)
__global__ __launch_bounds__(256) void cvt_kernel(const float* __restrict__ x,
        u16* __restrict__ xb, const float* __restrict__ W1, u16* __restrict__ Wt,
        const float* __restrict__ W2, u16* __restrict__ W2t,
        const int* __restrict__ ei, int* __restrict__ deg) {
    int b = blockIdx.x;
    if (b < G_DEG) {                                 // degree count (atomics)
        int j = b * 256 + threadIdx.x;
        if (j >= E_TOT) return;
        int dstn = (j < N_EDGES) ? ei[N_EDGES + j] : (j - N_EDGES);
        atomicAdd(&deg[dstn], 1);
    } else if (b < G_DEG + G_XCVT) {
        int t = (b - G_DEG) * 256 + threadIdx.x;     // one per 8 elements
        if (t >= N_NODES * F_IN / 8) return;
        const float4* xp = (const float4*)x + (size_t)t * 2;
        float4 v0 = xp[0], v1 = xp[1];
        uint4 o;
        o.x = (u32)f2bf(v0.x) | ((u32)f2bf(v0.y) << 16);
        o.y = (u32)f2bf(v0.z) | ((u32)f2bf(v0.w) << 16);
        o.z = (u32)f2bf(v1.x) | ((u32)f2bf(v1.y) << 16);
        o.w = (u32)f2bf(v1.z) | ((u32)f2bf(v1.w) << 16);
        ((uint4*)xb)[t] = o;
    } else if (b < G_DEG + G_XCVT + G_WCVT) {
        int t = (b - G_DEG - G_XCVT) * 256 + threadIdx.x;    // 65536 total
        int n = t & 255, k = t >> 8;                 // coalesced reads
        Wt[(size_t)n * F_IN + k] = f2bf(W1[(size_t)k * HC + n]);
    } else {
        int t = (b - G_DEG - G_XCVT - G_WCVT) * 256 + threadIdx.x;  // 8192
        if (t >= HC * CH) return;
        int n = t & 255, k = t >> 8;
        W2t[(size_t)n * CH + k] = f2bf(W2[(size_t)k * HC + n]);
    }
}

// ================= GEMM1 via MFMA bf16: ht8 = fp8(x @ W1), natural store
__global__ __launch_bounds__(256) void gemm1_mfma(const u16* __restrict__ xb,
        const u16* __restrict__ Wt, u8* __restrict__ ht8) {
    const int row0 = blockIdx.x * 32;
    const int t    = threadIdx.x;
    const int wave = t >> 6;
    const int lane = t & 63;
    const int l16  = lane & 15;
    const int quad = lane >> 4;
    const int nb   = wave * 64;

    f32x4 acc[2][4];
    #pragma unroll
    for (int m = 0; m < 2; ++m)
        #pragma unroll
        for (int n = 0; n < 4; ++n) acc[m][n] = (f32x4){0.f, 0.f, 0.f, 0.f};

    const u16* a0p = xb + (size_t)(row0 + l16) * F_IN;        // M-tile 0
    const u16* a1p = a0p + 16 * F_IN;                         // M-tile 1
    const u16* bp  = Wt + (size_t)(nb + l16) * F_IN;          // N-tile stride 16*F_IN

    #pragma unroll 1
    for (int k0 = 0; k0 < F_IN; k0 += 32) {
        const int ko = k0 + quad * 8;
        bf16x8 a0 = *(const bf16x8*)(a0p + ko);
        bf16x8 a1 = *(const bf16x8*)(a1p + ko);
        bf16x8 b0 = *(const bf16x8*)(bp + 0 * 16 * F_IN + ko);
        bf16x8 b1 = *(const bf16x8*)(bp + 1 * 16 * F_IN + ko);
        bf16x8 b2 = *(const bf16x8*)(bp + 2 * 16 * F_IN + ko);
        bf16x8 b3 = *(const bf16x8*)(bp + 3 * 16 * F_IN + ko);
        acc[0][0] = __builtin_amdgcn_mfma_f32_16x16x32_bf16(a0, b0, acc[0][0], 0, 0, 0);
        acc[0][1] = __builtin_amdgcn_mfma_f32_16x16x32_bf16(a0, b1, acc[0][1], 0, 0, 0);
        acc[0][2] = __builtin_amdgcn_mfma_f32_16x16x32_bf16(a0, b2, acc[0][2], 0, 0, 0);
        acc[0][3] = __builtin_amdgcn_mfma_f32_16x16x32_bf16(a0, b3, acc[0][3], 0, 0, 0);
        acc[1][0] = __builtin_amdgcn_mfma_f32_16x16x32_bf16(a1, b0, acc[1][0], 0, 0, 0);
        acc[1][1] = __builtin_amdgcn_mfma_f32_16x16x32_bf16(a1, b1, acc[1][1], 0, 0, 0);
        acc[1][2] = __builtin_amdgcn_mfma_f32_16x16x32_bf16(a1, b2, acc[1][2], 0, 0, 0);
        acc[1][3] = __builtin_amdgcn_mfma_f32_16x16x32_bf16(a1, b3, acc[1][3], 0, 0, 0);
    }

    #pragma unroll
    for (int m = 0; m < 2; ++m) {
        #pragma unroll
        for (int r = 0; r < 4; ++r) {
            int row = row0 + m * 16 + quad * 4 + r;
            if (row < N_NODES) {
                u8* hr = ht8 + (size_t)row * HC;
                #pragma unroll
                for (int n = 0; n < 4; ++n) {
                    int col = nb + n * 16 + l16;
                    hr[col] = f2fp8(acc[m][n][r]);   // natural layout
                }
            }
        }
    }
}

// ================= GEMM2 via MFMA bf16: ht8 = fp8(hmb @ W2), K=32 single step
__global__ __launch_bounds__(256) void gemm2_mfma(const u16* __restrict__ hmb,
        const u16* __restrict__ W2t, u8* __restrict__ ht8) {
    const int row0 = blockIdx.x * 32;
    const int t    = threadIdx.x;
    const int wave = t >> 6;
    const int lane = t & 63;
    const int l16  = lane & 15;
    const int quad = lane >> 4;
    const int nb   = wave * 64;
    const int ko   = quad * 8;

    const u16* a0p = hmb + (size_t)(row0 + l16) * CH;
    const u16* a1p = a0p + 16 * CH;
    const u16* bp  = W2t + (size_t)(nb + l16) * CH;

    bf16x8 a0 = *(const bf16x8*)(a0p + ko);
    bf16x8 a1 = *(const bf16x8*)(a1p + ko);
    bf16x8 b0 = *(const bf16x8*)(bp + 0 * 16 * CH + ko);
    bf16x8 b1 = *(const bf16x8*)(bp + 1 * 16 * CH + ko);
    bf16x8 b2 = *(const bf16x8*)(bp + 2 * 16 * CH + ko);
    bf16x8 b3 = *(const bf16x8*)(bp + 3 * 16 * CH + ko);

    f32x4 z = (f32x4){0.f, 0.f, 0.f, 0.f};
    f32x4 acc[2][4];
    acc[0][0] = __builtin_amdgcn_mfma_f32_16x16x32_bf16(a0, b0, z, 0, 0, 0);
    acc[0][1] = __builtin_amdgcn_mfma_f32_16x16x32_bf16(a0, b1, z, 0, 0, 0);
    acc[0][2] = __builtin_amdgcn_mfma_f32_16x16x32_bf16(a0, b2, z, 0, 0, 0);
    acc[0][3] = __builtin_amdgcn_mfma_f32_16x16x32_bf16(a0, b3, z, 0, 0, 0);
    acc[1][0] = __builtin_amdgcn_mfma_f32_16x16x32_bf16(a1, b0, z, 0, 0, 0);
    acc[1][1] = __builtin_amdgcn_mfma_f32_16x16x32_bf16(a1, b1, z, 0, 0, 0);
    acc[1][2] = __builtin_amdgcn_mfma_f32_16x16x32_bf16(a1, b2, z, 0, 0, 0);
    acc[1][3] = __builtin_amdgcn_mfma_f32_16x16x32_bf16(a1, b3, z, 0, 0, 0);

    #pragma unroll
    for (int m = 0; m < 2; ++m) {
        #pragma unroll
        for (int r = 0; r < 4; ++r) {
            int row = row0 + m * 16 + quad * 4 + r;
            if (row < N_NODES) {
                u8* hr = ht8 + (size_t)row * HC;
                #pragma unroll
                for (int n = 0; n < 4; ++n) {
                    int col = nb + n * 16 + l16;
                    hr[col] = f2fp8(acc[m][n][r]);   // natural layout
                }
            }
        }
    }
}

// ================= alpha from fp8 ht (head-major): thread = node
__global__ __launch_bounds__(256) void alpha_t_kernel(const u8* __restrict__ ht8,
        const float* __restrict__ a_src, const float* __restrict__ a_dst,
        float* __restrict__ asrc, float* __restrict__ adst) {
    __shared__ float sas[HC], sad[HC];
    for (int i = threadIdx.x; i < HC; i += 256) {
        sas[i] = a_src[i];
        sad[i] = a_dst[i];
    }
    __syncthreads();
    int node = blockIdx.x * 256 + threadIdx.x;
    if (node >= N_NODES) return;
    const uint2* hp = (const uint2*)(ht8 + (size_t)node * HC);   // 32 uint2
    float s1[NHEAD], s2[NHEAD];
    #pragma unroll
    for (int h = 0; h < NHEAD; ++h) {
        float t1 = 0.f, t2 = 0.f;
        #pragma unroll
        for (int i = 0; i < 4; ++i) {
            uint2 v = hp[h * 4 + i];                  // channels i*8 .. i*8+7
            f32x2 p01 = __builtin_amdgcn_cvt_pk_f32_fp8(v.x, false);
            f32x2 p23 = __builtin_amdgcn_cvt_pk_f32_fp8(v.x, true);
            f32x2 p45 = __builtin_amdgcn_cvt_pk_f32_fp8(v.y, false);
            f32x2 p67 = __builtin_amdgcn_cvt_pk_f32_fp8(v.y, true);
            const float* s1p = &sas[h * CH + i * 8];  // broadcast (same addr)
            const float* s2p = &sad[h * CH + i * 8];
            t1 += p01.x * s1p[0] + p01.y * s1p[1] + p23.x * s1p[2] + p23.y * s1p[3]
                + p45.x * s1p[4] + p45.y * s1p[5] + p67.x * s1p[6] + p67.y * s1p[7];
            t2 += p01.x * s2p[0] + p01.y * s2p[1] + p23.x * s2p[2] + p23.y * s2p[3]
                + p45.x * s2p[4] + p45.y * s2p[5] + p67.x * s2p[6] + p67.y * s2p[7];
        }
        s1[h] = t1; s2[h] = t2;
    }
    float4* o1 = (float4*)(asrc + (size_t)node * NHEAD);
    float4* o2 = (float4*)(adst + (size_t)node * NHEAD);
    o1[0] = make_float4(s1[0], s1[1], s1[2], s1[3]);
    o1[1] = make_float4(s1[4], s1[5], s1[6], s1[7]);
    o2[0] = make_float4(s2[0], s2[1], s2[2], s2[3]);
    o2[1] = make_float4(s2[4], s2[5], s2[6], s2[7]);
}

// ================= CSR build =================
__device__ __forceinline__ int wave_incl_scan(int v, int lane) {
    #pragma unroll
    for (int d = 1; d < 64; d <<= 1) {
        int u = __shfl_up(v, d, 64);
        if (lane >= d) v += u;
    }
    return v;
}

__global__ __launch_bounds__(256) void scan1_kernel(const int* __restrict__ deg,
        int* __restrict__ rowptr, int* __restrict__ partials) {
    const int t    = blockIdx.x * 256 + threadIdx.x;
    const int lane = threadIdx.x & 63;
    const int wid  = threadIdx.x >> 6;
    int v = (t < N_NODES) ? deg[t] : 0;
    int inc = wave_incl_scan(v, lane);
    __shared__ int wtot[4];
    if (lane == 63) wtot[wid] = inc;
    __syncthreads();
    int woff = 0;
    #pragma unroll
    for (int i = 0; i < 4; ++i) woff += (i < wid) ? wtot[i] : 0;
    if (t < N_NODES) rowptr[t] = inc - v + woff;      // block-local exclusive
    if (threadIdx.x == 255) partials[blockIdx.x] = woff + inc;  // block total
}

__global__ __launch_bounds__(256) void scan2_kernel(int* __restrict__ partials) {
    const int t    = threadIdx.x;
    const int lane = t & 63;
    const int wid  = t >> 6;
    int v = (t < SCAN_BLOCKS) ? partials[t] : 0;
    int inc = wave_incl_scan(v, lane);
    __shared__ int wtot[4];
    if (lane == 63) wtot[wid] = inc;
    __syncthreads();
    int woff = 0;
    #pragma unroll
    for (int i = 0; i < 4; ++i) woff += (i < wid) ? wtot[i] : 0;
    __syncthreads();
    if (t < SCAN_BLOCKS) partials[t] = inc - v + woff;
}

__global__ __launch_bounds__(256) void scan3_kernel(int* __restrict__ rowptr,
        int* __restrict__ cursor, const int* __restrict__ partials) {
    const int t = blockIdx.x * 256 + threadIdx.x;
    if (t < N_NODES) {
        int v = rowptr[t] + partials[blockIdx.x];
        rowptr[t] = v;
        cursor[t] = v;
    } else if (t == N_NODES) {
        rowptr[N_NODES] = E_TOT;
    }
}

// u16 payload (src < 50000 < 65536): halves the random-store dirty-line
// traffic that made scatter ~60us (WRITE_SIZE was 55MB = 850k line events).
__global__ __launch_bounds__(256) void scatter_kernel(const int* __restrict__ ei,
        int* __restrict__ cursor, u16* __restrict__ csr_src) {
    int j = blockIdx.x * 256 + threadIdx.x;
    if (j >= E_TOT) return;
    int src, dst;
    if (j < N_EDGES) { src = ei[j]; dst = ei[N_EDGES + j]; }
    else             { src = j - N_EDGES; dst = src; }
    int pos = atomicAdd(&cursor[dst], 1);
    csr_src[pos] = (u16)src;
}

// ================= fused attention: one WAVE per dst node, QUARTER per edge.
// r18: r17 showed more MLP buys nothing (58us flat, VALUBusy 70%) -> cut the
// per-edge issue cost instead: uniform trip count (invalid slots neutralized
// by as=-1e30 -> w=exp->0; stale hv stays finite since fp8 rows are NaN-free),
// v_pk_fma_f32 via __builtin_elementwise_fma (16 fmac -> 8 pk_fma), u16 csr.
__global__ __launch_bounds__(256) void attn_kernel(const int* __restrict__ rowptr,
        const u16* __restrict__ csr_src, const float* __restrict__ asrc,
        const float* __restrict__ adst, const u8* __restrict__ ht8,
        const float* __restrict__ b, u16* __restrict__ out) {
    const int wid = (blockIdx.x * 256 + threadIdx.x) >> 6;   // dst node
    if (wid >= N_NODES) return;
    const int dst  = wid;
    const int lane = threadIdx.x & 63;
    const int q    = lane >> 4;          // quarter -> edge offset
    const int l16  = lane & 15;
    const int h    = l16 >> 1;           // owned head
    const float ad_own = adst[dst * NHEAD + h];
    const u8* hbase = ht8 + l16 * 16;    // this lane's 16B slice of each row

    f32x2 acc2[8];
    #pragma unroll
    for (int i = 0; i < 8; ++i) acc2[i] = (f32x2){0.f, 0.f};
    float wsum = 0.f;

    const int p0 = rowptr[dst], p1 = rowptr[dst + 1];
    const int nt = (p1 - p0 + 7) >> 3;   // uniform trips (8 edges per trip)

    float asA = -1e30f, asB = -1e30f;
    uint4 hvA = make_uint4(0u, 0u, 0u, 0u), hvB = make_uint4(0u, 0u, 0u, 0u);
    int e = p0 + q;                      // this quarter's edges: stride 4
    if (e < p1) {
        int s = (int)csr_src[e];
        asA = asrc[s * NHEAD + h];
        hvA = *(const uint4*)(hbase + ((size_t)s << 8));
    }
    if (e + 4 < p1) {
        int s = (int)csr_src[e + 4];
        asB = asrc[s * NHEAD + h];
        hvB = *(const uint4*)(hbase + ((size_t)s << 8));
    }

    for (int it = 0; it < nt; ++it) {
        float aA = asA; uint4 hA = hvA;
        float aB = asB; uint4 hB = hvB;
        asA = -1e30f; asB = -1e30f;
        if (e + 8 < p1) {                 // prefetch next trip (predicated)
            int s = (int)csr_src[e + 8];
            asA = asrc[s * NHEAD + h];
            hvA = *(const uint4*)(hbase + ((size_t)s << 8));
        }
        if (e + 12 < p1) {
            int s = (int)csr_src[e + 12];
            asB = asrc[s * NHEAD + h];
            hvB = *(const uint4*)(hbase + ((size_t)s << 8));
        }
        {   // consume A (edge e); invalid slots: w==0, finite hv -> no-op
            float x = aA + ad_own;
            x = x > 0.f ? x : NEG_SLOPE * x;
            float w = __expf(x);
            wsum += w;
            f32x2 w2; w2.x = w; w2.y = w;
            acc2[0] = __builtin_elementwise_fma(w2, __builtin_amdgcn_cvt_pk_f32_fp8(hA.x, false), acc2[0]);
            acc2[1] = __builtin_elementwise_fma(w2, __builtin_amdgcn_cvt_pk_f32_fp8(hA.x, true ), acc2[1]);
            acc2[2] = __builtin_elementwise_fma(w2, __builtin_amdgcn_cvt_pk_f32_fp8(hA.y, false), acc2[2]);
            acc2[3] = __builtin_elementwise_fma(w2, __builtin_amdgcn_cvt_pk_f32_fp8(hA.y, true ), acc2[3]);
            acc2[4] = __builtin_elementwise_fma(w2, __builtin_amdgcn_cvt_pk_f32_fp8(hA.z, false), acc2[4]);
            acc2[5] = __builtin_elementwise_fma(w2, __builtin_amdgcn_cvt_pk_f32_fp8(hA.z, true ), acc2[5]);
            acc2[6] = __builtin_elementwise_fma(w2, __builtin_amdgcn_cvt_pk_f32_fp8(hA.w, false), acc2[6]);
            acc2[7] = __builtin_elementwise_fma(w2, __builtin_amdgcn_cvt_pk_f32_fp8(hA.w, true ), acc2[7]);
        }
        {   // consume B (edge e+4)
            float x = aB + ad_own;
            x = x > 0.f ? x : NEG_SLOPE * x;
            float w = __expf(x);
            wsum += w;
            f32x2 w2; w2.x = w; w2.y = w;
            acc2[0] = __builtin_elementwise_fma(w2, __builtin_amdgcn_cvt_pk_f32_fp8(hB.x, false), acc2[0]);
            acc2[1] = __builtin_elementwise_fma(w2, __builtin_amdgcn_cvt_pk_f32_fp8(hB.x, true ), acc2[1]);
            acc2[2] = __builtin_elementwise_fma(w2, __builtin_amdgcn_cvt_pk_f32_fp8(hB.y, false), acc2[2]);
            acc2[3] = __builtin_elementwise_fma(w2, __builtin_amdgcn_cvt_pk_f32_fp8(hB.y, true ), acc2[3]);
            acc2[4] = __builtin_elementwise_fma(w2, __builtin_amdgcn_cvt_pk_f32_fp8(hB.z, false), acc2[4]);
            acc2[5] = __builtin_elementwise_fma(w2, __builtin_amdgcn_cvt_pk_f32_fp8(hB.z, true ), acc2[5]);
            acc2[6] = __builtin_elementwise_fma(w2, __builtin_amdgcn_cvt_pk_f32_fp8(hB.w, false), acc2[6]);
            acc2[7] = __builtin_elementwise_fma(w2, __builtin_amdgcn_cvt_pk_f32_fp8(hB.w, true ), acc2[7]);
        }
        e += 8;
    }

    // ---- fold the four quarters (same (h,chblk), disjoint edges) ----
    #pragma unroll
    for (int i = 0; i < 8; ++i) {
        acc2[i].x += __shfl_xor(acc2[i].x, 16, 64);
        acc2[i].y += __shfl_xor(acc2[i].y, 16, 64);
        acc2[i].x += __shfl_xor(acc2[i].x, 32, 64);
        acc2[i].y += __shfl_xor(acc2[i].y, 32, 64);
    }
    wsum += __shfl_xor(wsum, 16, 64);
    wsum += __shfl_xor(wsum, 32, 64);

    // ---- per-head softmax normalize (v_pk_mul) ----
    float winv = 1.0f / wsum;
    f32x2 winv2; winv2.x = winv; winv2.y = winv;
    #pragma unroll
    for (int i = 0; i < 8; ++i) acc2[i] *= winv2;

    // ---- sum over heads: lane = 2h + blk, fold bits 1..3 ----
    #pragma unroll
    for (int i = 0; i < 8; ++i) {
        acc2[i].x += __shfl_xor(acc2[i].x, 2, 64);
        acc2[i].y += __shfl_xor(acc2[i].y, 2, 64);
        acc2[i].x += __shfl_xor(acc2[i].x, 4, 64);
        acc2[i].y += __shfl_xor(acc2[i].y, 4, 64);
        acc2[i].x += __shfl_xor(acc2[i].x, 8, 64);
        acc2[i].y += __shfl_xor(acc2[i].y, 8, 64);
    }

    // ---- lane 0: channels 0..15, lane 1: channels 16..31 ----
    if (lane < 2) {
        const int c0 = lane * 16;
        const float4* bp4 = (const float4*)(b + c0);
        float4 b0 = bp4[0], b1 = bp4[1], b2 = bp4[2], b3 = bp4[3];
        float bb[16] = {b0.x, b0.y, b0.z, b0.w, b1.x, b1.y, b1.z, b1.w,
                        b2.x, b2.y, b2.z, b2.w, b3.x, b3.y, b3.z, b3.w};
        u32 d[8];
        #pragma unroll
        for (int i = 0; i < 8; ++i) {
            float v0 = acc2[i].x * 0.125f + bb[2 * i];
            float v1 = acc2[i].y * 0.125f + bb[2 * i + 1];
            v0 = v0 > 0.f ? v0 : (__expf(v0) - 1.f);
            v1 = v1 > 0.f ? v1 : (__expf(v1) - 1.f);
            d[i] = (u32)f2bf(v0) | ((u32)f2bf(v1) << 16);
        }
        uint4* op = (uint4*)(out + (size_t)dst * CH + c0);
        op[0] = make_uint4(d[0], d[1], d[2], d[3]);
        op[1] = make_uint4(d[4], d[5], d[6], d[7]);
    }
}

// ================= output head: 4 nodes/block (1 wave each), log_softmax
__global__ __launch_bounds__(256) void out_kernel(const u16* __restrict__ hf,
        const float* __restrict__ Wo, const float* __restrict__ bo,
        float* __restrict__ out) {
    const int wave = threadIdx.x >> 6;
    const int lane = threadIdx.x & 63;
    const int n    = blockIdx.x * 4 + wave;
    __shared__ float hs[4][CH];
    if (n < N_NODES && lane < CH) hs[wave][lane] = bflo((u32)hf[n * CH + lane]);
    __syncthreads();
    if (n >= N_NODES) return;
    float logit = -INFINITY;
    if (lane < OUT_C) {
        float a = bo[lane];
        #pragma unroll
        for (int k = 0; k < CH; ++k) a += hs[wave][k] * Wo[k * OUT_C + lane];
        logit = a;
    }
    float m = logit;
    #pragma unroll
    for (int off = 32; off; off >>= 1) m = fmaxf(m, __shfl_xor(m, off, 64));
    float ex = (lane < OUT_C) ? __expf(logit - m) : 0.f;
    float ssum = ex;
    #pragma unroll
    for (int off = 32; off; off >>= 1) ssum += __shfl_xor(ssum, off, 64);
    if (lane < OUT_C) out[(size_t)n * OUT_C + lane] = logit - m - __logf(ssum);
}

extern "C" void kernel_launch(void* const* d_in, const int* in_sizes, int n_in,
                              void* d_out, int out_size, void* d_ws, size_t ws_size,
                              hipStream_t stream) {
    const float* x      = (const float*)d_in[0];
    const int*   ei     = (const int*)  d_in[1];
    const float* W1     = (const float*)d_in[2];
    const float* a_src1 = (const float*)d_in[3];
    const float* a_dst1 = (const float*)d_in[4];
    const float* b1     = (const float*)d_in[5];
    const float* W2     = (const float*)d_in[6];
    const float* a_src2 = (const float*)d_in[7];
    const float* a_dst2 = (const float*)d_in[8];
    const float* b2     = (const float*)d_in[9];
    const float* Wo     = (const float*)d_in[10];
    const float* bo     = (const float*)d_in[11];
    float* out = (float*)d_out;

    // workspace carve-up (256B-aligned)
    char* ws = (char*)d_ws;
    size_t off = 0;
    auto carve = [&](size_t bytes) { char* p = ws + off; off += (bytes + 255) & ~(size_t)255; return p; };
    u8*    ht8     = (u8*)   carve((size_t)N_NODES * HC);          // 12.8 MB (fp8, head-major)
    u16*   xb      = (u16*)  carve((size_t)N_PAD * F_IN * 2);      // 25.6 MB (bf16 x, padded)
    u16*   Wt      = (u16*)  carve((size_t)HC * F_IN * 2);         // 128 KB (bf16 W1^T)
    u16*   W2t     = (u16*)  carve((size_t)HC * CH * 2);           // 16 KB (bf16 W2^T)
    float* asrc    = (float*)carve((size_t)N_NODES * NHEAD * 4);   // 1.6 MB
    float* adst    = (float*)carve((size_t)N_NODES * NHEAD * 4);
    u16*   hmid    = (u16*)  carve((size_t)N_PAD * CH * 2);        // 3.2 MB (bf16)
    u16*   hout    = (u16*)  carve((size_t)N_NODES * CH * 2);      // 3.2 MB (bf16)
    int*   deg     = (int*)  carve((size_t)N_NODES * 4);
    int*   rowptr  = (int*)  carve((size_t)(N_NODES + 1) * 4);
    int*   cursor  = (int*)  carve((size_t)N_NODES * 4);
    u16*   csr_src = (u16*)  carve((size_t)E_TOT * 2);             // 1.7 MB (u16!)
    int*   partials= (int*)  carve((size_t)SCAN_BLOCKS * 4);

    const int g_cvt   = G_DEG + G_XCVT + G_WCVT + G_WCVT2;   // 9859
    const int g_gemm  = (N_NODES + 31) / 32;                 // 1563
    const int g_node  = (N_NODES + 255) / 256;               // 196
    const int g_edge  = (E_TOT + 255) / 256;                 // 3321
    const int g_attn  = (N_NODES * 64 + 255) / 256;          // 12500 (wave/dst)
    const int g_out   = (N_NODES + 3) / 4;                   // 12500

    // ---------- prep + CSR build (deg fused into cvt) ----------
    (void)hipMemsetAsync(deg, 0, (size_t)N_NODES * 4, stream);
    cvt_kernel<<<g_cvt, 256, 0, stream>>>(x, xb, W1, Wt, W2, W2t, ei, deg);
    scan1_kernel<<<SCAN_BLOCKS, 256, 0, stream>>>(deg, rowptr, partials);
    scan2_kernel<<<1, 256, 0, stream>>>(partials);
    scan3_kernel<<<SCAN_BLOCKS, 256, 0, stream>>>(rowptr, cursor, partials);
    scatter_kernel<<<g_edge, 256, 0, stream>>>(ei, cursor, csr_src);

    // ---------- layer 1 ----------
    gemm1_mfma<<<g_gemm, 256, 0, stream>>>(xb, Wt, ht8);
    alpha_t_kernel<<<g_node, 256, 0, stream>>>(ht8, a_src1, a_dst1, asrc, adst);
    attn_kernel<<<g_attn, 256, 0, stream>>>(rowptr, csr_src, asrc, adst, ht8, b1, hmid);

    // ---------- layer 2 ----------
    gemm2_mfma<<<g_gemm, 256, 0, stream>>>(hmid, W2t, ht8);
    alpha_t_kernel<<<g_node, 256, 0, stream>>>(ht8, a_src2, a_dst2, asrc, adst);
    attn_kernel<<<g_attn, 256, 0, stream>>>(rowptr, csr_src, asrc, adst, ht8, b2, hout);

    // ---------- output head ----------
    out_kernel<<<g_out, 256, 0, stream>>>(hout, Wo, bo, out);
}